// Round 7
// baseline (577.620 us; speedup 1.0000x reference)
//
#include <hip/hip_runtime.h>
#include <hip/hip_bf16.h>

typedef __attribute__((ext_vector_type(8))) short short8;
typedef __attribute__((ext_vector_type(4))) float f32x4;
using bf16 = __hip_bfloat16;

__device__ inline unsigned short f2bfu(float x) {
  bf16 h = __float2bfloat16(x);
  return __builtin_bit_cast(unsigned short, h);
}

// async global->LDS 16B copy (lands at wave-uniform base + lane*16)
__device__ __forceinline__ void gll16(const void* g, void* l) {
  __builtin_amdgcn_global_load_lds(
      (const __attribute__((address_space(1))) unsigned int*)g,
      (__attribute__((address_space(3))) unsigned int*)l, 16, 0, 0);
}

// ---------------- cast fp32 -> bf16, 4 elems/thread ----------------
__global__ __launch_bounds__(256) void cast_f32_bf16(const float4* __restrict__ src,
                                                     unsigned long long* __restrict__ dst,
                                                     int n4) {
  int i = blockIdx.x * 256 + threadIdx.x;
  if (i >= n4) return;
  float4 v = src[i];
  unsigned long long r = (unsigned long long)f2bfu(v.x)
                       | ((unsigned long long)f2bfu(v.y) << 16)
                       | ((unsigned long long)f2bfu(v.z) << 32)
                       | ((unsigned long long)f2bfu(v.w) << 48);
  dst[i] = r;
}

// ---------------- GEMM: C[M,N] = A[M,K] * B[N,K]^T ----------------
// 256x256 tile, BK=64, 8 waves (2Mx4N). Read-ahead pipelined 4-phase schedule:
// ds_reads for phase i+1 issued in phase i (counted lgkmcnt), staging 2 K-tiles
// deep (counted vmcnt(4), never drained to 0 in-loop). Cross-wave visibility of
// staged tiles: every vmcnt drain is followed by s_barrier BEFORE any wave reads
// the staged region. XOR-swizzled LDS via pre-swizzled global_load_lds sources.
__device__ inline void store_cvt(float* p, float v) { *p = v; }
__device__ inline void store_cvt(bf16* p, float v) { *p = __float2bfloat16(v); }

template <typename OutT>
__global__ __launch_bounds__(512, 2) void gemm_bt(const bf16* __restrict__ A,
                                                  const bf16* __restrict__ B,
                                                  OutT* __restrict__ C,
                                                  int M, int N, int K) {
  __shared__ __align__(16) bf16 lds[2][2][256 * 64];  // [op A/B][dbuf][256 rows][64 k] = 128 KiB
  const int tid = threadIdx.x;
  const int wave = tid >> 6, lane = tid & 63;
  const int wm = wave >> 2, wn = wave & 3;          // 2 M-waves x 4 N-waves; per-wave 128x64 out
  const int quad = lane >> 4, l16 = lane & 15;

  // XCD-aware swizzle (nwg % 8 == 0 for all our shapes -> simple form is bijective)
  const int nwg = gridDim.x * gridDim.y;
  int lin = blockIdx.y * gridDim.x + blockIdx.x;
  lin = (lin & 7) * (nwg >> 3) + (lin >> 3);
  const int n0 = (lin % gridDim.x) << 8;
  const int m0 = (lin / gridDim.x) << 8;

  // staging pattern: pass p writes LDS chunk (p*512+tid)*16 LINEARLY (gll requirement);
  // source is pre-swizzled with the same involution the reads use: byte ^= (row&7)<<4.
  int off_el[2], dst_b[2];
#pragma unroll
  for (int p = 0; p < 2; p++) {
    int d = (p * 512 + tid) * 16;
    int dl = d ^ (((d >> 7) & 7) << 4);
    off_el[p] = (dl >> 7) * K + ((dl & 127) >> 1);
    dst_b[p] = d;
  }

  auto STAGE = [&](const bf16* __restrict__ P, int op, int bfi, int half, int rowBase, int kt) {
    const bf16* src = P + (size_t)rowBase * K + kt;
    char* dst = (char*)&lds[op][bfi][half * 8192];
    gll16(src + off_el[0], dst + dst_b[0]);
    gll16(src + off_el[1], dst + dst_b[1]);
  };
  auto FRAG = [&](int op, int bfi, int row, int cb) -> short8 {
    int byteoff = ((row << 7) + cb) ^ ((row & 7) << 4);
    return *(const short8*)((const char*)&lds[op][bfi][0] + byteoff);
  };

  f32x4 acc[8][4] = {};
  const int nkt = K >> 6;

  short8 alo[4][2], ahi[4][2], b01[2][2], b23[2][2];

  // prologue: stage tile0 + tile1 fully (16 loads); wait tile0 + barrier; preload alo,b01.
  STAGE(A, 0, 0, 0, m0, 0);
  STAGE(A, 0, 0, 1, m0 + 128, 0);
  STAGE(B, 1, 0, 0, n0, 0);
  STAGE(B, 1, 0, 1, n0 + 128, 0);
  {
    const int k1 = (nkt > 1) ? 64 : 0;
    STAGE(A, 0, 1, 0, m0, k1);
    STAGE(A, 0, 1, 1, m0 + 128, k1);
    STAGE(B, 1, 1, 0, n0, k1);
    STAGE(B, 1, 1, 1, n0 + 128, k1);
  }
  asm volatile("s_waitcnt vmcnt(8)" ::: "memory");
  __builtin_amdgcn_s_barrier();
  __builtin_amdgcn_sched_barrier(0);
#pragma unroll
  for (int mf = 0; mf < 4; mf++)
#pragma unroll
    for (int ks = 0; ks < 2; ks++)
      alo[mf][ks] = FRAG(0, 0, wm * 128 + mf * 16 + l16, ks * 64 + quad * 16);
#pragma unroll
  for (int nf = 0; nf < 2; nf++)
#pragma unroll
    for (int ks = 0; ks < 2; ks++)
      b01[nf][ks] = FRAG(1, 0, wn * 64 + nf * 16 + l16, ks * 64 + quad * 16);

  for (int t = 0; t < nkt; ++t) {
    const int bfi = t & 1, nbf = bfi ^ 1;
    const int kt2 = min(t + 2, nkt - 1) << 6;

    // ---- p0: issue ahi reads; MFMA mlo x n01 (alo,b01 drained by lgkm(8))
#pragma unroll
    for (int mf = 0; mf < 4; mf++)
#pragma unroll
      for (int ks = 0; ks < 2; ks++)
        ahi[mf][ks] = FRAG(0, bfi, wm * 128 + 64 + mf * 16 + l16, ks * 64 + quad * 16);
    asm volatile("s_waitcnt lgkmcnt(8)" ::: "memory");
    __builtin_amdgcn_sched_barrier(0);
    __builtin_amdgcn_s_setprio(1);
#pragma unroll
    for (int mf = 0; mf < 4; mf++)
#pragma unroll
      for (int nf = 0; nf < 2; nf++)
#pragma unroll
        for (int ks = 0; ks < 2; ks++)
          acc[mf][nf] = __builtin_amdgcn_mfma_f32_16x16x32_bf16(alo[mf][ks], b01[nf][ks], acc[mf][nf], 0, 0, 0);
    __builtin_amdgcn_s_setprio(0);
    __builtin_amdgcn_sched_barrier(0);
    __builtin_amdgcn_s_barrier();
    __builtin_amdgcn_sched_barrier(0);

    // ---- p1: issue b23 reads; MFMA mhi x n01 (ahi drained by lgkm(4))
#pragma unroll
    for (int nf = 0; nf < 2; nf++)
#pragma unroll
      for (int ks = 0; ks < 2; ks++)
        b23[nf][ks] = FRAG(1, bfi, wn * 64 + 32 + nf * 16 + l16, ks * 64 + quad * 16);
    asm volatile("s_waitcnt lgkmcnt(4)" ::: "memory");
    __builtin_amdgcn_sched_barrier(0);
    __builtin_amdgcn_s_setprio(1);
#pragma unroll
    for (int mf = 0; mf < 4; mf++)
#pragma unroll
      for (int nf = 0; nf < 2; nf++)
#pragma unroll
        for (int ks = 0; ks < 2; ks++)
          acc[4 + mf][nf] = __builtin_amdgcn_mfma_f32_16x16x32_bf16(ahi[mf][ks], b01[nf][ks], acc[4 + mf][nf], 0, 0, 0);
    __builtin_amdgcn_s_setprio(0);
    __builtin_amdgcn_sched_barrier(0);
    __builtin_amdgcn_s_barrier();
    __builtin_amdgcn_sched_barrier(0);

    // ---- p2: stage A from tile t+2 (A[bfi] fully consumed; p1 end barrier passed);
    //          MFMA mhi x n23 (b23 drained by lgkm(0))
    STAGE(A, 0, bfi, 0, m0, kt2);
    STAGE(A, 0, bfi, 1, m0 + 128, kt2);
    asm volatile("s_waitcnt lgkmcnt(0)" ::: "memory");
    __builtin_amdgcn_sched_barrier(0);
    __builtin_amdgcn_s_setprio(1);
#pragma unroll
    for (int mf = 0; mf < 4; mf++)
#pragma unroll
      for (int nf = 0; nf < 2; nf++)
#pragma unroll
        for (int ks = 0; ks < 2; ks++)
          acc[4 + mf][2 + nf] = __builtin_amdgcn_mfma_f32_16x16x32_bf16(ahi[mf][ks], b23[nf][ks], acc[4 + mf][2 + nf], 0, 0, 0);
    __builtin_amdgcn_s_setprio(0);
    __builtin_amdgcn_sched_barrier(0);
    __builtin_amdgcn_s_barrier();
    __builtin_amdgcn_sched_barrier(0);

    // ---- p3: vmcnt(4) = everything through tile t+1 landed (keeps t+2 A in flight);
    //          barrier makes all waves' staged slices visible; then read next b01,
    //          stage B from tile t+2, MFMA mlo x n23, read next alo (regs freed).
    asm volatile("s_waitcnt vmcnt(4)" ::: "memory");
    __builtin_amdgcn_s_barrier();
    __builtin_amdgcn_sched_barrier(0);
#pragma unroll
    for (int nf = 0; nf < 2; nf++)
#pragma unroll
      for (int ks = 0; ks < 2; ks++)
        b01[nf][ks] = FRAG(1, nbf, wn * 64 + nf * 16 + l16, ks * 64 + quad * 16);
    STAGE(B, 1, bfi, 0, n0, kt2);
    STAGE(B, 1, bfi, 1, n0 + 128, kt2);
    __builtin_amdgcn_sched_barrier(0);
    __builtin_amdgcn_s_setprio(1);
#pragma unroll
    for (int mf = 0; mf < 4; mf++)
#pragma unroll
      for (int nf = 0; nf < 2; nf++)
#pragma unroll
        for (int ks = 0; ks < 2; ks++)
          acc[mf][2 + nf] = __builtin_amdgcn_mfma_f32_16x16x32_bf16(alo[mf][ks], b23[nf][ks], acc[mf][2 + nf], 0, 0, 0);
    __builtin_amdgcn_s_setprio(0);
    __builtin_amdgcn_sched_barrier(0);
#pragma unroll
    for (int mf = 0; mf < 4; mf++)
#pragma unroll
      for (int ks = 0; ks < 2; ks++)
        alo[mf][ks] = FRAG(0, nbf, wm * 128 + mf * 16 + l16, ks * 64 + quad * 16);
    __builtin_amdgcn_s_barrier();
    __builtin_amdgcn_sched_barrier(0);
  }

  // epilogue
#pragma unroll
  for (int mf = 0; mf < 8; mf++)
#pragma unroll
    for (int nf = 0; nf < 4; nf++) {
      int col = n0 + wn * 64 + nf * 16 + l16;
#pragma unroll
      for (int r = 0; r < 4; r++) {
        int row = m0 + wm * 128 + mf * 16 + quad * 4 + r;
        store_cvt(&C[(size_t)row * N + col], acc[mf][nf][r]);
      }
    }
}

// ---------------- RMSNorm + RoPE: one wave per (token, slot) row ----------------
__global__ __launch_bounds__(256) void norm_rope(const bf16* __restrict__ qkv,
                                                 bf16* __restrict__ qb,
                                                 bf16* __restrict__ kb) {
  const int lane = threadIdx.x & 63;
  const int gw = (blockIdx.x * 256 + threadIdx.x) >> 6;
  const int nw = (gridDim.x * 256) >> 6;
  const float inv_freq = __expf(-(float)lane * (9.210340371976184f / 64.0f));
  for (int row = gw; row < 20 * 8192; row += nw) {
    const int slot = row >> 13, token = row & 8191;
    const int b = token >> 11, t = token & 2047;
    const bf16* src = qkv + (size_t)token * 3072 + slot * 128;
    float x1 = __bfloat162float(src[lane]);
    float x2 = __bfloat162float(src[lane + 64]);
    float ss = x1 * x1 + x2 * x2;
#pragma unroll
    for (int m = 1; m < 64; m <<= 1) ss += __shfl_xor(ss, m, 64);
    float rinv = rsqrtf(ss * (1.0f / 128.0f) + 1.1920929e-7f);
    x1 *= rinv; x2 *= rinv;
    float c, s;
    __sincosf((float)t * inv_freq, &s, &c);
    float o1 = x1 * c + x2 * s;
    float o2 = x2 * c - x1 * s;
    bf16* dst;
    if (slot < 16) {
      o1 *= 0.08838834764831845f;  // fold 1/sqrt(D) into q
      o2 *= 0.08838834764831845f;
      dst = qb + (((size_t)(b * 16 + slot)) * 2048 + t) * 128;
    } else {
      dst = kb + (((size_t)(b * 4 + (slot - 16))) * 2048 + t) * 128;
    }
    dst[lane] = __float2bfloat16(o1);
    dst[lane + 64] = __float2bfloat16(o2);
  }
}

// ---------------- V transpose straight from qkv: -> (s, d, t), s = b*4+hkv ----------------
__global__ __launch_bounds__(256) void transpose_v(const bf16* __restrict__ qkv,
                                                   bf16* __restrict__ vout) {
  __shared__ __align__(16) bf16 til[64][144];
  const int tid = threadIdx.x;
  const int s = blockIdx.y;                 // b*4 + hkv
  const int b = s >> 2, hkv = s & 3;
  const bf16* src = qkv + ((size_t)(b * 2048 + blockIdx.x * 64)) * 3072 + 2560 + hkv * 128;
  bf16* dst = vout + (size_t)s * 128 * 2048 + blockIdx.x * 64;
#pragma unroll
  for (int p = 0; p < 4; p++) {
    int idx = p * 256 + tid;
    *(uint4*)&til[idx >> 4][(idx & 15) * 8] =
        *(const uint4*)&src[(size_t)(idx >> 4) * 3072 + (idx & 15) * 8];
  }
  __syncthreads();
  const int ds = tid & 127;
  const int hs = tid >> 7;
#pragma unroll
  for (int p = 0; p < 4; p++) {
    int c8 = (p * 2 + hs) * 8;
    short8 v;
#pragma unroll
    for (int j = 0; j < 8; j++) v[j] = *(const short*)&til[c8 + j][ds];
    *(short8*)&dst[(size_t)ds * 2048 + c8] = v;
  }
}

// ---------------- causal GQA flash attention (persistent, head-paired) ----------------
// GQA sharing: heads 2hp and 2hp+1 share K/V (hkv = hp>>1). Each block processes a
// head PAIR: one K/V staging + one set of Ks/Vt LDS reads feeds BOTH heads' MFMAs
// (halves LDS-read bytes per MFMA -- the kernel is LDS-pipe-bound).
// 4 waves / 64 q-rows per item; items = qt(32) x bp(32) = 1024; 512 blocks,
// block i does {i, 1023-i}: qt sum = 31 so every block runs exactly 33 K-tiles.
// LDS 54.3 KB -> 2 blocks/CU. Fixed-shift softmax (|s| <= sqrt(128) < 12).
__global__ __launch_bounds__(256, 2) void flash_attn(const bf16* __restrict__ qb,
                                                     const bf16* __restrict__ kb,
                                                     const bf16* __restrict__ vtg,
                                                     bf16* __restrict__ attnb) {
  __shared__ __align__(16) bf16 Ks[64][136];       // 17.4 KB
  __shared__ __align__(16) bf16 Vt[128][72];       // 18.4 KB  [d][t]
  __shared__ __align__(16) bf16 Ps[2][4][16][72];  // 18.4 KB  per-head, per-wave slab

  const int tid = threadIdx.x;
  const int w = tid >> 6, lane = tid & 63;
  const int quad = lane >> 4, l16 = lane & 15;
  const int krow = tid >> 4, kc8 = (tid & 15) * 8;   // krow 0..15, stages rows +16j
  const int vrow = tid >> 3, vc8 = (tid & 7) * 8;    // vrow 0..31, stages rows +32j

  for (int it = 0; it < 2; it++) {
    const int pi = it == 0 ? (int)blockIdx.x : 1023 - (int)blockIdx.x;
    const int qt = pi >> 5, bp = pi & 31;
    const int b = bp >> 3, hp = bp & 7;
    const int h0 = hp * 2, hkv = hp >> 1;
    const int q0 = qt * 64;
    const bf16* Q0 = qb + ((size_t)(b * 16 + h0) * 2048 + q0) * 128;
    const bf16* Q1 = Q0 + (size_t)2048 * 128;
    const bf16* Kp = kb + (size_t)(b * 4 + hkv) * 2048 * 128;
    const bf16* Vg = vtg + (size_t)(b * 4 + hkv) * 128 * 2048;
    const int qw = q0 + w * 16;
    const int qrow = qw + quad * 4;

    // Q fragments for both heads (A-layout), pre-scaled by 1/sqrt(D)
    short8 aq0[4], aq1[4];
#pragma unroll
    for (int dk = 0; dk < 4; dk++) {
      aq0[dk] = *(const short8*)&Q0[(size_t)(w * 16 + l16) * 128 + dk * 32 + quad * 8];
      aq1[dk] = *(const short8*)&Q1[(size_t)(w * 16 + l16) * 128 + dk * 32 + quad * 8];
    }

    f32x4 o0[8] = {}, o1[8] = {};
    float l0[4] = {0.f, 0.f, 0.f, 0.f}, l1[4] = {0.f, 0.f, 0.f, 0.f};

    const int ntiles = qt + 1;
    uint4 ka[4], va[4];
#pragma unroll
    for (int j = 0; j < 4; j++) {
      ka[j] = *(const uint4*)&Kp[(size_t)(krow + 16 * j) * 128 + kc8];
      va[j] = *(const uint4*)&Vg[(size_t)(vrow + 32 * j) * 2048 + vc8];
    }

    for (int kt = 0; kt < ntiles; kt++) {
      const int kv0 = kt * 64;
#pragma unroll
      for (int j = 0; j < 4; j++) {
        *(uint4*)&Ks[krow + 16 * j][kc8] = ka[j];
        *(uint4*)&Vt[vrow + 32 * j][vc8] = va[j];
      }
      __syncthreads();

      // prefetch next tile; flies during compute
      const int nkv0 = min(kv0 + 64, (ntiles - 1) * 64);
#pragma unroll
      for (int j = 0; j < 4; j++) {
        ka[j] = *(const uint4*)&Kp[(size_t)(nkv0 + krow + 16 * j) * 128 + kc8];
        va[j] = *(const uint4*)&Vg[(size_t)(vrow + 32 * j) * 2048 + nkv0 + vc8];
      }

      if (kv0 <= qw + 15) {  // wave-uniform causal skip
        // QK^T for both heads off one Ks read
        f32x4 s0[4] = {}, s1[4] = {};
#pragma unroll
        for (int nt = 0; nt < 4; nt++)
#pragma unroll
          for (int dk = 0; dk < 4; dk++) {
            short8 bk = *(const short8*)&Ks[nt * 16 + l16][dk * 32 + quad * 8];
            s0[nt] = __builtin_amdgcn_mfma_f32_16x16x32_bf16(aq0[dk], bk, s0[nt], 0, 0, 0);
            s1[nt] = __builtin_amdgcn_mfma_f32_16x16x32_bf16(aq1[dk], bk, s1[nt], 0, 0, 0);
          }

        const bool dtile = (kv0 + 63 > qw);
#pragma unroll
        for (int nt = 0; nt < 4; nt++) {
          const int kcol = kv0 + nt * 16 + l16;
#pragma unroll
          for (int r = 0; r < 4; r++) {
            const bool mask = dtile && kcol > qrow + r;
            float p0 = __expf(s0[nt][r] - 12.0f);
            float p1 = __expf(s1[nt][r] - 12.0f);
            if (mask) { p0 = 0.f; p1 = 0.f; }
            l0[r] += p0; l1[r] += p1;
            Ps[0][w][quad * 4 + r][nt * 16 + l16] = __float2bfloat16(p0);
            Ps[1][w][quad * 4 + r][nt * 16 + l16] = __float2bfloat16(p1);
          }
        }
        __threadfence_block();  // intra-wave RAW on per-wave Ps slabs

        short8 ap0[2], ap1[2];
#pragma unroll
        for (int kk = 0; kk < 2; kk++) {
          ap0[kk] = *(const short8*)&Ps[0][w][l16][kk * 32 + quad * 8];
          ap1[kk] = *(const short8*)&Ps[1][w][l16][kk * 32 + quad * 8];
        }
        // PV for both heads off one Vt read
#pragma unroll
        for (int vt = 0; vt < 8; vt++)
#pragma unroll
          for (int kk = 0; kk < 2; kk++) {
            short8 bv = *(const short8*)&Vt[vt * 16 + l16][kk * 32 + quad * 8];
            o0[vt] = __builtin_amdgcn_mfma_f32_16x16x32_bf16(ap0[kk], bv, o0[vt], 0, 0, 0);
            o1[vt] = __builtin_amdgcn_mfma_f32_16x16x32_bf16(ap1[kk], bv, o1[vt], 0, 0, 0);
          }
      }
      __syncthreads();
    }

    // epilogue: register-only (safe to overlap with next item's staging)
#pragma unroll
    for (int r = 0; r < 4; r++) {
#pragma unroll
      for (int mm = 1; mm < 16; mm <<= 1) {
        l0[r] += __shfl_xor(l0[r], mm, 64);
        l1[r] += __shfl_xor(l1[r], mm, 64);
      }
    }
#pragma unroll
    for (int r = 0; r < 4; r++) {
      float inv0 = 1.0f / l0[r];
      float inv1 = 1.0f / l1[r];
      int trow = qw + quad * 4 + r;
      size_t base0 = ((size_t)b * 2048 + trow) * 2048 + h0 * 128;
      size_t base1 = base0 + 128;
#pragma unroll
      for (int vt = 0; vt < 8; vt++) {
        attnb[base0 + vt * 16 + l16] = __float2bfloat16(o0[vt][r] * inv0);
        attnb[base1 + vt * 16 + l16] = __float2bfloat16(o1[vt][r] * inv1);
      }
    }
  }
}

__global__ void finalize(float* out) {
  if (threadIdx.x == 0 && blockIdx.x == 0) out[(size_t)8192 * 2048] = 0.0f;
}

extern "C" void kernel_launch(void* const* d_in, const int* in_sizes, int n_in,
                              void* d_out, int out_size, void* d_ws, size_t ws_size,
                              hipStream_t stream) {
  const float* x  = (const float*)d_in[0];
  const float* Wq = (const float*)d_in[1];
  const float* Wk = (const float*)d_in[2];
  const float* Wv = (const float*)d_in[3];
  const float* Wo = (const float*)d_in[4];
  float* out = (float*)d_out;

  char* ws = (char*)d_ws;
  bf16* xb    = (bf16*)(ws);               // 33.5 MB
  bf16* wqkv  = (bf16*)(ws + 33554432);    // 12.6 MB (dead after QKV gemm)
  bf16* vtb   = (bf16*)(ws + 33554432);    // 8.4 MB, aliases wqkv
  bf16* wob   = (bf16*)(ws + 46137344);    // 8.4 MB
  bf16* qkvb  = (bf16*)(ws + 54525952);    // 50.3 MB
  bf16* qb    = (bf16*)(ws + 104857600);   // 33.5 MB
  bf16* kb    = (bf16*)(ws + 138412032);   // 8.4 MB
  bf16* attnb = qkvb;                      // alias: qkv dead after attention inputs built

  cast_f32_bf16<<<16384, 256, 0, stream>>>((const float4*)x,  (unsigned long long*)xb, 4194304);
  cast_f32_bf16<<<4096,  256, 0, stream>>>((const float4*)Wq, (unsigned long long*)wqkv, 1048576);
  cast_f32_bf16<<<1024,  256, 0, stream>>>((const float4*)Wk, (unsigned long long*)(wqkv + 2048 * 2048), 262144);
  cast_f32_bf16<<<1024,  256, 0, stream>>>((const float4*)Wv, (unsigned long long*)(wqkv + 2560 * 2048), 262144);
  cast_f32_bf16<<<4096,  256, 0, stream>>>((const float4*)Wo, (unsigned long long*)wob, 1048576);

  gemm_bt<bf16><<<dim3(12, 32), 512, 0, stream>>>(xb, wqkv, qkvb, 8192, 3072, 2048);
  norm_rope<<<4096, 256, 0, stream>>>(qkvb, qb, kb);
  transpose_v<<<dim3(32, 16), 256, 0, stream>>>(qkvb, vtb);
  flash_attn<<<512, 256, 0, stream>>>(qb, kb, vtb, attnb);
  gemm_bt<float><<<dim3(8, 32), 512, 0, stream>>>(attnb, wob, out, 8192, 2048, 2048);
  finalize<<<1, 64, 0, stream>>>(out);
}